// Round 6
// baseline (1018.994 us; speedup 1.0000x reference)
//
#include <hip/hip_runtime.h>
#include <hip/hip_bf16.h>

using bf16 = __hip_bfloat16;
using short8 = __attribute__((ext_vector_type(8))) short;
using f32x4  = __attribute__((ext_vector_type(4))) float;

#define BATCH 128
#define CCH   256
#define HWSZ  784
#define NPOS  100352
#define NWIN  2048

__device__ __forceinline__ ushort f2u(float f) {
    bf16 h = __float2bfloat16(f);
    return *reinterpret_cast<ushort*>(&h);
}
__device__ __forceinline__ float u2f(ushort u) {
    bf16 h;
    *reinterpret_cast<ushort*>(&h) = u;
    return __bfloat162float(h);
}
// XOR swizzle for 64-col ushort LDS tiles (128B rows): b128 reads 2-way.
__device__ __forceinline__ int swz64(int row, int col) {
    return row * 64 + (col ^ ((row & 7) << 3));
}
// Async 16B/lane global->LDS (dest = wave-uniform base + lane*16).
__device__ __forceinline__ void gl_lds16(const void* g, void* l) {
    __builtin_amdgcn_global_load_lds(
        (const __attribute__((address_space(1))) void*)g,
        (__attribute__((address_space(3))) void*)l, 16, 0, 0);
}

// ---------------------------------------------------------------------------
// Weight fp32 -> bf16 pre-convert (layout: see offsets in kernel_launch).
// ---------------------------------------------------------------------------
__global__ __launch_bounds__(256) void wcvt_k(const float* __restrict__ w1a,
                                              const float* __restrict__ w2a,
                                              const float* __restrict__ pw,
                                              const float* __restrict__ w1b,
                                              const float* __restrict__ w2b,
                                              const float* __restrict__ qw,
                                              const float* __restrict__ qs,
                                              const float* __restrict__ qbi,
                                              const float* __restrict__ dqw,
                                              const float* __restrict__ dqs,
                                              const float* __restrict__ dqb,
                                              ushort* __restrict__ out) {
    int i = blockIdx.x * 256 + threadIdx.x;
    if (i >= 610048) return;
    float v;
    if (i < 131072)      v = w1a[i];
    else if (i < 262144) v = w2a[i - 131072];
    else if (i < 327680) v = pw[i - 262144];
    else if (i < 458752) v = w1b[i - 327680];
    else if (i < 589824) v = w2b[i - 458752];
    else if (i < 606208) { int j = i - 589824; v = qs[j >> 5] * qw[j]; }
    else if (i < 609408) { int j = i - 606208; v = dqs[j / 25] * dqw[j]; }
    else if (i < 609920) v = qbi[i - 609408];
    else                 v = dqb[i - 609920];
    out[i] = f2u(v);
}

// ---------------------------------------------------------------------------
// Expand attention biases: abx[h][n][m] = ab[h][bidx[n*49+m]]  (8 x 49 x 49)
// ---------------------------------------------------------------------------
__global__ __launch_bounds__(256) void abx_k(const float* __restrict__ ab,
                                             const int* __restrict__ bidx,
                                             float* __restrict__ abx) {
    int i = blockIdx.x * 256 + threadIdx.x;
    if (i >= 8 * 2401) return;
    int h = i / 2401, r = i - h * 2401;
    abx[i] = ab[h * 49 + bidx[r]];
}

// ---------------------------------------------------------------------------
// NCHW fp32 -> NHWC bf16 transpose.
// ---------------------------------------------------------------------------
__global__ __launch_bounds__(256) void tin_k(const float* __restrict__ X,
                                             ushort* __restrict__ O) {
    __shared__ ushort tile[256][113];
    const int pc = blockIdx.x, b = blockIdx.y;
    const int t = threadIdx.x;
    const size_t xbase = (size_t)b * 256 * 784 + pc * 112;
    for (int r = 0; r < 112; ++r) {
        int idx = r * 256 + t;
        int c = idx / 112, p = idx - c * 112;
        tile[c][p] = f2u(X[xbase + (size_t)c * 784 + p]);
    }
    __syncthreads();
    const size_t obase = ((size_t)b * 784 + pc * 112) * 256;
    for (int r = 0; r < 112; ++r) {
        int idx = r * 256 + t;
        int p = idx >> 8, c = idx & 255;
        O[obase + (size_t)p * 256 + c] = tile[c][p];
    }
}

// ---------------------------------------------------------------------------
// Depthwise 3x3 + affine + residual, NHWC bf16.
// ---------------------------------------------------------------------------
__global__ __launch_bounds__(256) void dw3n_k(const ushort* __restrict__ X,
                                              const float* __restrict__ Wg,
                                              const float* __restrict__ sc,
                                              const float* __restrict__ bi,
                                              ushort* __restrict__ O) {
    const int h = blockIdx.x, b = blockIdx.y;
    const int c = threadIdx.x;
    float wv[9];
#pragma unroll
    for (int k = 0; k < 9; ++k) wv[k] = Wg[c * 9 + k];
    const float s = sc[c], bb = bi[c];
    const size_t base = (size_t)b * 784 * 256;
    for (int w = 0; w < 28; ++w) {
        float acc = 0.f, ctr = 0.f;
#pragma unroll
        for (int dh = -1; dh <= 1; ++dh) {
            int hh = h + dh;
            if (hh < 0 || hh >= 28) continue;
#pragma unroll
            for (int dw = -1; dw <= 1; ++dw) {
                int ww = w + dw;
                if (ww < 0 || ww >= 28) continue;
                float xv = u2f(X[base + (size_t)(hh * 28 + ww) * 256 + c]);
                if (dh == 0 && dw == 0) ctr = xv;
                acc += wv[(dh + 1) * 3 + (dw + 1)] * xv;
            }
        }
        O[base + (size_t)(h * 28 + w) * 256 + c] = f2u(ctr + s * acc + bb);
    }
}

// ---------------------------------------------------------------------------
// MFMA GEMM, NHWC. global_load_lds width=16 staging + 2-phase double-buffer:
// per K-step {STAGE(next buf) ; ds_read+MFMA(cur) ; barrier ; flip}.
// Hazards: STAGE(t) overwrites the buffer whose reads drained (lgkmcnt) at
// barrier(t-1); its data is consumed after barrier(t) drains vmcnt. One
// barrier per step is sufficient; DMA overlaps the MFMA phase.
// ---------------------------------------------------------------------------
template <int IC, int OC, bool RELU_OUT, bool RESID, bool NCHW_OUT>
__global__ __launch_bounds__(256) void gemm_k(const ushort* __restrict__ X,
                                              const ushort* __restrict__ Wb,
                                              const float* __restrict__ sc,
                                              const float* __restrict__ bi,
                                              const ushort* __restrict__ res,
                                              void* __restrict__ outp) {
    __shared__ ushort As[2][128 * 32];
    __shared__ ushort Bs[2][128 * 32];
    const int t = threadIdx.x;
    const int pos0 = blockIdx.x * 128;
    const int oc0  = blockIdx.y * 128;
    const int wave = t >> 6, lane = t & 63;
    const int qd = lane >> 4, ln = lane & 15;
    const int pw = (wave >> 1) * 64, ow = (wave & 1) * 64;
    // staging: lane -> (row = lane>>2, phys slot = lane&3); source column is
    // the LOGICAL slot (lane&3) ^ ((lane>>3)&3)  [= (row>>1)&3 per 16-row blk]
    const int grow = lane >> 2;
    const int gcol = ((lane & 3) ^ ((lane >> 3) & 3)) * 8;
    // fragment reads: logical slot qd at row ..+ln -> phys slot qd^((ln>>1)&3)
    const int xsl = (qd ^ ((ln >> 1) & 3)) * 8;

    f32x4 acc[4][4];
#pragma unroll
    for (int i = 0; i < 4; ++i)
#pragma unroll
        for (int j = 0; j < 4; ++j) acc[i][j] = (f32x4)0.f;

    constexpr int NT = IC / 32;
    // prologue: stage K-step 0 into buf 0
#pragma unroll
    for (int r = 0; r < 2; ++r) {
        const int rowbase = wave * 16 + r * 64;
        gl_lds16(&X[(size_t)(pos0 + rowbase + grow) * IC + gcol], &As[0][rowbase * 32]);
        gl_lds16(&Wb[(size_t)(oc0 + rowbase + grow) * IC + gcol], &Bs[0][rowbase * 32]);
    }
    __syncthreads();

    int cur = 0;
#pragma unroll
    for (int kt = 0; kt < NT; ++kt) {
        if (kt + 1 < NT) {
            const int k0 = (kt + 1) * 32;
#pragma unroll
            for (int r = 0; r < 2; ++r) {
                const int rowbase = wave * 16 + r * 64;
                gl_lds16(&X[(size_t)(pos0 + rowbase + grow) * IC + k0 + gcol],
                         &As[cur ^ 1][rowbase * 32]);
                gl_lds16(&Wb[(size_t)(oc0 + rowbase + grow) * IC + k0 + gcol],
                         &Bs[cur ^ 1][rowbase * 32]);
            }
        }
        short8 bfr[4];
#pragma unroll
        for (int j = 0; j < 4; ++j)
            bfr[j] = *(const short8*)&Bs[cur][(ow + j * 16 + ln) * 32 + xsl];
#pragma unroll
        for (int i = 0; i < 4; ++i) {
            short8 a = *(const short8*)&As[cur][(pw + i * 16 + ln) * 32 + xsl];
#pragma unroll
            for (int j = 0; j < 4; ++j)
                acc[i][j] = __builtin_amdgcn_mfma_f32_16x16x32_bf16(a, bfr[j], acc[i][j], 0, 0, 0);
        }
        __syncthreads();
        cur ^= 1;
    }

#pragma unroll
    for (int j = 0; j < 4; ++j) {
        const int oc = oc0 + ow + j * 16 + ln;
        const float s = sc[oc], bb = bi[oc];
#pragma unroll
        for (int i = 0; i < 4; ++i) {
#pragma unroll
            for (int r = 0; r < 4; ++r) {
                const int pos = pos0 + pw + i * 16 + qd * 4 + r;
                float v = s * acc[i][j][r] + bb;
                if constexpr (RELU_OUT) v = fmaxf(v, 0.f);
                if constexpr (RESID) v += u2f(res[(size_t)pos * 256 + oc]);
                if constexpr (NCHW_OUT) {
                    int bb2 = pos / 784, hw = pos - bb2 * 784;
                    ((float*)outp)[((size_t)bb2 * 256 + oc) * 784 + hw] = v;
                } else {
                    ((ushort*)outp)[(size_t)pos * OC + oc] = f2u(v);
                }
            }
        }
    }
}

// ---------------------------------------------------------------------------
// Cascaded group attention (round-5 structure, 176us) + head-top register
// prefetch of abx bias and next-X slice: both were on the per-head critical
// path (abx between logits MFMA and softmax; X inside emit). Issued at head
// top they drain under the qkv phase / barrier 1.
// ---------------------------------------------------------------------------
__global__ __launch_bounds__(256, 4) void attn_k(const ushort* __restrict__ X,
                                                 const ushort* __restrict__ qwb,
                                                 const ushort* __restrict__ qbb,
                                                 const ushort* __restrict__ dwvb,
                                                 const ushort* __restrict__ dbbb,
                                                 const float* __restrict__ abx,
                                                 ushort* __restrict__ Y) {
    __shared__ ushort featB[64 * 32];   // feat bf16, pos-major (slot-swizzled)
    __shared__ ushort q2t[64 * 32];     // q after dw5x5 (slot-swizzled)
    __shared__ ushort kt[64 * 32];      // k (slot-swizzled)
    __shared__ ushort vd[32 * 64];      // v, ch-major (swz64)
    __shared__ ushort pt[64 * 64];      // probs, pos-major (swz64)
    __shared__ float  uni[16 * 121];    // q ch-major, 2-wide zero halo (11x11)
    __shared__ ushort dwv[3200];        // all-head dw taps, pre-scaled bf16
    __shared__ ushort qb[512];          // all-head qkv bias bf16
    __shared__ ushort dbl[128];         // all-head dw bias bf16
    __shared__ int    posmap[49];
    __shared__ int    puni[49];

    const int t = threadIdx.x;
    const int w = blockIdx.x;
    const int b = w >> 4, wh = (w >> 2) & 3, ww = w & 3;
    const int wv_ = t >> 6, lane = t & 63;
    const int ln = lane & 15, qd = lane >> 4;
    const int msl = (ln >> 1) & 3;            // slot-XOR for rows ..+ln
    const int fsl = (qd ^ msl) * 8;           // phys frag offset (ushorts)
    const int nbase = 16 * wv_ + qd * 4;

    if (t < 49) {
        int pi = t / 7, pj = t - pi * 7;
        posmap[t] = b * 784 + (wh * 7 + pi) * 28 + ww * 7 + pj;
        puni[t] = (pi + 2) * 11 + (pj + 2);
    }
    // zero-init (pads never rewritten; swizzles map zero->zero)
    for (int i = t; i < 16 * 121; i += 256) uni[i] = 0.f;
    for (int i = t; i < 64 * 32; i += 256) { q2t[i] = 0; kt[i] = 0; featB[i] = 0; }
    for (int i = t; i < 32 * 64; i += 256) vd[i] = 0;
    for (int i = t; i < 64 * 64; i += 256) pt[i] = 0;
    // stage all-head weights once
    for (int i = t; i < 3200; i += 256) dwv[i] = dwvb[i];
    for (int i = t; i < 512; i += 256) qb[i] = qbb[i];
    if (t < 128) dbl[t] = dbbb[t];
    // feat(head0) = x slice 0 (swizzled store; positions >=49 stay zero)
    for (int i = t; i < 1568; i += 256) {
        int p = i >> 5, c = i & 31;
        int pi = p / 7, pj = p - pi * 7;
        featB[p * 32 + (c & 7) + (((c >> 3) ^ ((p >> 1) & 3)) << 3)] =
            X[(size_t)(b * 784 + (wh * 7 + pi) * 28 + ww * 7 + pj) * 256 + c];
    }
    __syncthreads();

    const int arow = (16 * wv_ + ln) * 32 + fsl;  // swizzled A-frag offset

    for (int head = 0; head < 8; ++head) {
        // ---- register prefetches (depend only on head/lane; they drain at
        //      barrier 1, off the post-barrier critical path) ----
        float bias[4][4];
#pragma unroll
        for (int j = 0; j < 4; ++j) {
            int m = 16 * j + ln;
#pragma unroll
            for (int r = 0; r < 4; ++r) {
                int n = nbase + r;
                bias[j][r] = (n < 49 && m < 49) ? abx[head * 2401 + n * 49 + m] : 0.f;
            }
        }
        ushort xnx[4][2];
#pragma unroll
        for (int r = 0; r < 4; ++r) {
            int n = nbase + r;
            if (head < 7 && n < 49) {
#pragma unroll
                for (int dt = 0; dt < 2; ++dt)
                    xnx[r][dt] = X[(size_t)posmap[n] * 256 + (head + 1) * 32 + 16 * dt + ln];
            } else {
                xnx[r][0] = 0; xnx[r][1] = 0;
            }
        }

        // ---- qkv: D[o][p] = W'[o][:]·feat[p][:] + b ; wave = o-tile ----
        {
            short8 afr = *(const short8*)&qwb[head * 2048 + (16 * wv_ + ln) * 32 + qd * 8];
            f32x4 acc[4];
#pragma unroll
            for (int j = 0; j < 4; ++j) acc[j] = (f32x4)0.f;
#pragma unroll
            for (int j = 0; j < 4; ++j) {
                short8 bfr = *(const short8*)&featB[(16 * j + ln) * 32 + fsl];
                acc[j] = __builtin_amdgcn_mfma_f32_16x16x32_bf16(afr, bfr, acc[j], 0, 0, 0);
            }
            float qbv[4];
#pragma unroll
            for (int r = 0; r < 4; ++r)
                qbv[r] = u2f(qb[head * 64 + 16 * wv_ + qd * 4 + r]);
#pragma unroll
            for (int j = 0; j < 4; ++j) {
                int p = 16 * j + ln;
                if (p >= 49) continue;
                if (wv_ == 0) {
                    int pu = puni[p];
#pragma unroll
                    for (int r = 0; r < 4; ++r)
                        uni[(qd * 4 + r) * 121 + pu] = acc[j][r] + qbv[r];
                } else if (wv_ == 1) {
                    // logical col qd*4+r -> slot qd>>1, within (qd&1)*4+r
#pragma unroll
                    for (int r = 0; r < 4; ++r)
                        kt[p * 32 + ((qd * 4 + r) & 7) + ((((qd >> 1)) ^ msl) << 3)] =
                            f2u(acc[j][r] + qbv[r]);
                } else {
#pragma unroll
                    for (int r = 0; r < 4; ++r)
                        vd[swz64((wv_ - 2) * 16 + qd * 4 + r, p)] =
                            f2u(acc[j][r] + qbv[r]);
                }
            }
        }
        __syncthreads();   // barrier 1: uni/kt/vd visible; prefetches drained

        // ---- dw5x5 on q: wave computes its own logit rows 16wv_..+15 ----
        {
            const int d = ln;            // fixed per lane -> taps in registers
            float tap[25];
#pragma unroll
            for (int u = 0; u < 25; ++u)
                tap[u] = u2f(dwv[head * 400 + d * 25 + u]);
            float db = u2f(dbl[head * 16 + d]);
#pragma unroll
            for (int k = 0; k < 4; ++k) {
                int p = 16 * wv_ + k * 4 + qd;
                int mq = (2 * k + (qd >> 1)) & 3;   // (p>>1)&3
                if (p < 49) {
                    const float* qp = &uni[d * 121 + (puni[p] - 24)];
                    float a = 0.f;
#pragma unroll
                    for (int u = 0; u < 5; ++u)
#pragma unroll
                        for (int v5 = 0; v5 < 5; ++v5)
                            a += tap[u * 5 + v5] * qp[u * 11 + v5];
                    q2t[p * 32 + (d & 7) + (((d >> 3) ^ mq) << 3)] = f2u(a + db);
                }
            }
        }
        // same-wave q2t write -> read below: DS in-order per wave, no barrier

        // ---- logits + in-register softmax + AV + emit (all per-wave) ----
        {
            short8 afr = *(const short8*)&q2t[arow];
            f32x4 acc[4];
#pragma unroll
            for (int j = 0; j < 4; ++j) acc[j] = (f32x4)0.f;
#pragma unroll
            for (int j = 0; j < 4; ++j) {
                short8 bfr = *(const short8*)&kt[(16 * j + ln) * 32 + fsl];
                acc[j] = __builtin_amdgcn_mfma_f32_16x16x32_bf16(afr, bfr, acc[j], 0, 0, 0);
            }
            float lg[4][4];
#pragma unroll
            for (int j = 0; j < 4; ++j) {
                int m = 16 * j + ln;
#pragma unroll
                for (int r = 0; r < 4; ++r) {
                    int n = nbase + r;
                    if (n < 49 && m < 49)
                        lg[j][r] = acc[j][r] * 0.25f + bias[j][r];
                    else
                        lg[j][r] = -3e38f;
                }
            }
            float mx[4], sm[4];
#pragma unroll
            for (int r = 0; r < 4; ++r)
                mx[r] = fmaxf(fmaxf(lg[0][r], lg[1][r]), fmaxf(lg[2][r], lg[3][r]));
#pragma unroll
            for (int s = 1; s <= 8; s <<= 1)
#pragma unroll
                for (int r = 0; r < 4; ++r)
                    mx[r] = fmaxf(mx[r], __shfl_xor(mx[r], s, 16));
#pragma unroll
            for (int r = 0; r < 4; ++r) sm[r] = 0.f;
#pragma unroll
            for (int j = 0; j < 4; ++j) {
                int m = 16 * j + ln;
#pragma unroll
                for (int r = 0; r < 4; ++r) {
                    float e = __expf(lg[j][r] - mx[r]);
                    sm[r] += e;
                    int n = nbase + r;
                    if (n < 49 && m < 49) pt[swz64(n, m)] = f2u(e);
                }
            }
#pragma unroll
            for (int s = 1; s <= 8; s <<= 1)
#pragma unroll
                for (int r = 0; r < 4; ++r)
                    sm[r] += __shfl_xor(sm[r], s, 16);
            float inv[4];
#pragma unroll
            for (int r = 0; r < 4; ++r) inv[r] = 1.f / sm[r];

            // AV: D[n][d] = pt[n][:]·vd[d][:]  (swz64 rows share column XOR)
            f32x4 av[2];
            av[0] = (f32x4)0.f; av[1] = (f32x4)0.f;
#pragma unroll
            for (int ks = 0; ks < 2; ++ks) {
                const int cs = (ks * 32 + qd * 8) ^ ((ln & 7) << 3);
                short8 pa = *(const short8*)&pt[(16 * wv_ + ln) * 64 + cs];
#pragma unroll
                for (int dt = 0; dt < 2; ++dt) {
                    short8 vb = *(const short8*)&vd[(16 * dt + ln) * 64 + cs];
                    av[dt] = __builtin_amdgcn_mfma_f32_16x16x32_bf16(pa, vb, av[dt], 0, 0, 0);
                }
            }
            // emit Y slice (ReLU'd for proj) + cascade feat update
#pragma unroll
            for (int r = 0; r < 4; ++r) {
                int n = nbase + r;
                if (n >= 49) continue;
                size_t pbase = (size_t)posmap[n] * 256;
                int mn = (2 * qd + (r >> 1)) & 3;   // (n>>1)&3
#pragma unroll
                for (int dt = 0; dt < 2; ++dt) {
                    int c = 16 * dt + ln;
                    float val = av[dt][r] * inv[r];
                    Y[pbase + head * 32 + c] = f2u(fmaxf(val, 0.f));
                    if (head < 7)
                        featB[n * 32 + (ln & 7) +
                              (((2 * dt + (ln >> 3)) ^ mn) << 3)] =
                            f2u(val + u2f(xnx[r][dt]));
                }
            }
        }
        __syncthreads();   // barrier 2: featB update visible; buffers reusable
    }
}

// ---------------------------------------------------------------------------
extern "C" void kernel_launch(void* const* d_in, const int* in_sizes, int n_in,
                              void* d_out, int out_size, void* d_ws, size_t ws_size,
                              hipStream_t stream) {
    const float* x       = (const float*)d_in[0];
    const float* dw0_w   = (const float*)d_in[1];
    const float* dw0_s   = (const float*)d_in[2];
    const float* dw0_b   = (const float*)d_in[3];
    const float* ffn0_w1 = (const float*)d_in[4];
    const float* ffn0_s1 = (const float*)d_in[5];
    const float* ffn0_b1 = (const float*)d_in[6];
    const float* ffn0_w2 = (const float*)d_in[7];
    const float* ffn0_s2 = (const float*)d_in[8];
    const float* ffn0_b2 = (const float*)d_in[9];
    const float* qkv_w   = (const float*)d_in[10];
    const float* qkv_s   = (const float*)d_in[11];
    const float* qkv_b   = (const float*)d_in[12];
    const float* dwq_w   = (const float*)d_in[13];
    const float* dwq_s   = (const float*)d_in[14];
    const float* dwq_b   = (const float*)d_in[15];
    const float* attn_b  = (const float*)d_in[16];
    const float* proj_w  = (const float*)d_in[17];
    const float* proj_s  = (const float*)d_in[18];
    const float* proj_b  = (const float*)d_in[19];
    const float* dw1_w   = (const float*)d_in[20];
    const float* dw1_s   = (const float*)d_in[21];
    const float* dw1_b   = (const float*)d_in[22];
    const float* ffn1_w1 = (const float*)d_in[23];
    const float* ffn1_s1 = (const float*)d_in[24];
    const float* ffn1_b1 = (const float*)d_in[25];
    const float* ffn1_w2 = (const float*)d_in[26];
    const float* ffn1_s2 = (const float*)d_in[27];
    const float* ffn1_b2 = (const float*)d_in[28];
    const int*   bidx    = (const int*)d_in[29];

    char* ws = (char*)d_ws;
    const size_t NEL = (size_t)NPOS * 256;
    ushort* wbf = (ushort*)ws;                          // 610048 ushorts
    float*  abx = (float*)(ws + 1220096);               // 76,832 B
    ushort* U0 = (ushort*)(ws + 1220096 + 76832);       // 16B-aligned
    ushort* U1 = U0 + NEL;
    ushort* U2 = U1 + NEL;
    ushort* H  = U2 + NEL;
    const ushort* w1a_b = wbf;
    const ushort* w2a_b = wbf + 131072;
    const ushort* prj_b = wbf + 262144;
    const ushort* w1b_b = wbf + 327680;
    const ushort* w2b_b = wbf + 458752;
    const ushort* qwb   = wbf + 589824;
    const ushort* dwvb  = wbf + 606208;
    const ushort* qbb   = wbf + 609408;
    const ushort* dbbb  = wbf + 609920;

    wcvt_k<<<2383, 256, 0, stream>>>(ffn0_w1, ffn0_w2, proj_w, ffn1_w1, ffn1_w2,
                                     qkv_w, qkv_s, qkv_b, dwq_w, dwq_s, dwq_b, wbf);
    abx_k<<<76, 256, 0, stream>>>(attn_b, bidx, abx);
    tin_k<<<dim3(7, BATCH), 256, 0, stream>>>(x, U0);
    dw3n_k<<<dim3(28, BATCH), 256, 0, stream>>>(U0, dw0_w, dw0_s, dw0_b, U1);
    gemm_k<256, 512, true, false, false>
        <<<dim3(784, 4), 256, 0, stream>>>(U1, w1a_b, ffn0_s1, ffn0_b1, nullptr, H);
    gemm_k<512, 256, false, true, false>
        <<<dim3(784, 2), 256, 0, stream>>>(H, w2a_b, ffn0_s2, ffn0_b2, U1, U2);
    attn_k<<<NWIN, 256, 0, stream>>>(U2, qwb, qbb, dwvb, dbbb, abx, U0);
    gemm_k<256, 256, false, true, false>
        <<<dim3(784, 2), 256, 0, stream>>>(U0, prj_b, proj_s, proj_b, U2, U1);
    dw3n_k<<<dim3(28, BATCH), 256, 0, stream>>>(U1, dw1_w, dw1_s, dw1_b, U2);
    gemm_k<256, 512, true, false, false>
        <<<dim3(784, 4), 256, 0, stream>>>(U2, w1b_b, ffn1_s1, ffn1_b1, nullptr, H);
    gemm_k<512, 256, false, true, true>
        <<<dim3(784, 2), 256, 0, stream>>>(H, w2b_b, ffn1_s2, ffn1_b2, U2, d_out);
}

// Round 8
// 965.884 us; speedup vs baseline: 1.0550x; 1.0550x over previous
//
#include <hip/hip_runtime.h>
#include <hip/hip_bf16.h>

using bf16 = __hip_bfloat16;
using short8 = __attribute__((ext_vector_type(8))) short;
using f32x4  = __attribute__((ext_vector_type(4))) float;

#define BATCH 128
#define CCH   256
#define HWSZ  784
#define NPOS  100352
#define NWIN  2048

__device__ __forceinline__ ushort f2u(float f) {
    bf16 h = __float2bfloat16(f);
    return *reinterpret_cast<ushort*>(&h);
}
__device__ __forceinline__ float u2f(ushort u) {
    bf16 h;
    *reinterpret_cast<ushort*>(&h) = u;
    return __bfloat162float(h);
}
// XOR swizzle for 64-col ushort LDS tiles (128B rows): b128 reads 2-way.
__device__ __forceinline__ int swz64(int row, int col) {
    return row * 64 + (col ^ ((row & 7) << 3));
}
// Async 16B/lane global->LDS (dest = wave-uniform base + lane*16).
__device__ __forceinline__ void gl_lds16(const void* g, void* l) {
    __builtin_amdgcn_global_load_lds(
        (const __attribute__((address_space(1))) void*)g,
        (__attribute__((address_space(3))) void*)l, 16, 0, 0);
}

// ---------------------------------------------------------------------------
// Weight fp32 -> bf16 pre-convert (layout: see offsets in kernel_launch).
// ---------------------------------------------------------------------------
__global__ __launch_bounds__(256) void wcvt_k(const float* __restrict__ w1a,
                                              const float* __restrict__ w2a,
                                              const float* __restrict__ pw,
                                              const float* __restrict__ w1b,
                                              const float* __restrict__ w2b,
                                              const float* __restrict__ qw,
                                              const float* __restrict__ qs,
                                              const float* __restrict__ qbi,
                                              const float* __restrict__ dqw,
                                              const float* __restrict__ dqs,
                                              const float* __restrict__ dqb,
                                              ushort* __restrict__ out) {
    int i = blockIdx.x * 256 + threadIdx.x;
    if (i >= 610048) return;
    float v;
    if (i < 131072)      v = w1a[i];
    else if (i < 262144) v = w2a[i - 131072];
    else if (i < 327680) v = pw[i - 262144];
    else if (i < 458752) v = w1b[i - 327680];
    else if (i < 589824) v = w2b[i - 458752];
    else if (i < 606208) { int j = i - 589824; v = qs[j >> 5] * qw[j]; }
    else if (i < 609408) { int j = i - 606208; v = dqs[j / 25] * dqw[j]; }
    else if (i < 609920) v = qbi[i - 609408];
    else                 v = dqb[i - 609920];
    out[i] = f2u(v);
}

// ---------------------------------------------------------------------------
// Expand attention biases: abx[h][n][m] = ab[h][bidx[n*49+m]]  (8 x 49 x 49)
// ---------------------------------------------------------------------------
__global__ __launch_bounds__(256) void abx_k(const float* __restrict__ ab,
                                             const int* __restrict__ bidx,
                                             float* __restrict__ abx) {
    int i = blockIdx.x * 256 + threadIdx.x;
    if (i >= 8 * 2401) return;
    int h = i / 2401, r = i - h * 2401;
    abx[i] = ab[h * 49 + bidx[r]];
}

// ---------------------------------------------------------------------------
// NCHW fp32 -> NHWC bf16 transpose.
// ---------------------------------------------------------------------------
__global__ __launch_bounds__(256) void tin_k(const float* __restrict__ X,
                                             ushort* __restrict__ O) {
    __shared__ ushort tile[256][113];
    const int pc = blockIdx.x, b = blockIdx.y;
    const int t = threadIdx.x;
    const size_t xbase = (size_t)b * 256 * 784 + pc * 112;
    for (int r = 0; r < 112; ++r) {
        int idx = r * 256 + t;
        int c = idx / 112, p = idx - c * 112;
        tile[c][p] = f2u(X[xbase + (size_t)c * 784 + p]);
    }
    __syncthreads();
    const size_t obase = ((size_t)b * 784 + pc * 112) * 256;
    for (int r = 0; r < 112; ++r) {
        int idx = r * 256 + t;
        int p = idx >> 8, c = idx & 255;
        O[obase + (size_t)p * 256 + c] = tile[c][p];
    }
}

// ---------------------------------------------------------------------------
// Depthwise 3x3 + affine + residual, NHWC bf16.
// ---------------------------------------------------------------------------
__global__ __launch_bounds__(256) void dw3n_k(const ushort* __restrict__ X,
                                              const float* __restrict__ Wg,
                                              const float* __restrict__ sc,
                                              const float* __restrict__ bi,
                                              ushort* __restrict__ O) {
    const int h = blockIdx.x, b = blockIdx.y;
    const int c = threadIdx.x;
    float wv[9];
#pragma unroll
    for (int k = 0; k < 9; ++k) wv[k] = Wg[c * 9 + k];
    const float s = sc[c], bb = bi[c];
    const size_t base = (size_t)b * 784 * 256;
    for (int w = 0; w < 28; ++w) {
        float acc = 0.f, ctr = 0.f;
#pragma unroll
        for (int dh = -1; dh <= 1; ++dh) {
            int hh = h + dh;
            if (hh < 0 || hh >= 28) continue;
#pragma unroll
            for (int dw = -1; dw <= 1; ++dw) {
                int ww = w + dw;
                if (ww < 0 || ww >= 28) continue;
                float xv = u2f(X[base + (size_t)(hh * 28 + ww) * 256 + c]);
                if (dh == 0 && dw == 0) ctr = xv;
                acc += wv[(dh + 1) * 3 + (dw + 1)] * xv;
            }
        }
        O[base + (size_t)(h * 28 + w) * 256 + c] = f2u(ctr + s * acc + bb);
    }
}

// ---------------------------------------------------------------------------
// MFMA GEMM, NHWC. global_load_lds width=16 + double-buffer with COUNTED
// vmcnt (T4): per step {STAGE(next) [4 DMA]; s_waitcnt vmcnt(4); barrier;
// ds_read+MFMA(cur); lgkmcnt(0); barrier}. The counted wait releases only
// tile t (oldest 4); tile t+1's DMAs fly across the compute phase.
// Round-6 lesson: __syncthreads here drains vmcnt(0) -> serializes the
// just-issued DMA after compute (dbuf-with-drain0 == no dbuf).
// Hazards: RAW = own vmcnt + barrier 1; WAR (STAGE(t+2) over buf read at t)
// = barrier 2 after reads drained to regs (lgkmcnt 0). Both barriers are in
// uniform control flow (NT compile-time) -> no divergent-barrier risk.
// ---------------------------------------------------------------------------
template <int IC, int OC, bool RELU_OUT, bool RESID, bool NCHW_OUT>
__global__ __launch_bounds__(256) void gemm_k(const ushort* __restrict__ X,
                                              const ushort* __restrict__ Wb,
                                              const float* __restrict__ sc,
                                              const float* __restrict__ bi,
                                              const ushort* __restrict__ res,
                                              void* __restrict__ outp) {
    __shared__ ushort As[2][128 * 32];
    __shared__ ushort Bs[2][128 * 32];
    const int t = threadIdx.x;
    const int pos0 = blockIdx.x * 128;
    const int oc0  = blockIdx.y * 128;
    const int wave = t >> 6, lane = t & 63;
    const int qd = lane >> 4, ln = lane & 15;
    const int pw = (wave >> 1) * 64, ow = (wave & 1) * 64;
    // staging: lane -> (row = lane>>2, phys slot = lane&3); source column is
    // the LOGICAL slot (lane&3) ^ ((lane>>3)&3)  [= (row>>1)&3 per 16-row blk]
    const int grow = lane >> 2;
    const int gcol = ((lane & 3) ^ ((lane >> 3) & 3)) * 8;
    // fragment reads: logical slot qd at row ..+ln -> phys slot qd^((ln>>1)&3)
    const int xsl = (qd ^ ((ln >> 1) & 3)) * 8;

    f32x4 acc[4][4];
#pragma unroll
    for (int i = 0; i < 4; ++i)
#pragma unroll
        for (int j = 0; j < 4; ++j) acc[i][j] = (f32x4)0.f;

    constexpr int NT = IC / 32;
    // prologue: stage tile 0 into buf 0 (4 DMA/wave)
#pragma unroll
    for (int r = 0; r < 2; ++r) {
        const int rowbase = wave * 16 + r * 64;
        gl_lds16(&X[(size_t)(pos0 + rowbase + grow) * IC + gcol], &As[0][rowbase * 32]);
        gl_lds16(&Wb[(size_t)(oc0 + rowbase + grow) * IC + gcol], &Bs[0][rowbase * 32]);
    }

    for (int kt = 0; kt < NT; ++kt) {
        const int cur = kt & 1;
        if (kt + 1 < NT) {
            const int k0 = (kt + 1) * 32;
#pragma unroll
            for (int r = 0; r < 2; ++r) {
                const int rowbase = wave * 16 + r * 64;
                gl_lds16(&X[(size_t)(pos0 + rowbase + grow) * IC + k0 + gcol],
                         &As[cur ^ 1][rowbase * 32]);
                gl_lds16(&Wb[(size_t)(oc0 + rowbase + grow) * IC + k0 + gcol],
                         &Bs[cur ^ 1][rowbase * 32]);
            }
            asm volatile("s_waitcnt vmcnt(4)" ::: "memory");  // tile kt landed
        } else {
            asm volatile("s_waitcnt vmcnt(0)" ::: "memory");  // last tile
        }
        __builtin_amdgcn_sched_barrier(0);
        __builtin_amdgcn_s_barrier();          // all waves' tile-kt DMA landed
        __builtin_amdgcn_sched_barrier(0);

        short8 bfr[4];
#pragma unroll
        for (int j = 0; j < 4; ++j)
            bfr[j] = *(const short8*)&Bs[cur][(ow + j * 16 + ln) * 32 + xsl];
#pragma unroll
        for (int i = 0; i < 4; ++i) {
            short8 a = *(const short8*)&As[cur][(pw + i * 16 + ln) * 32 + xsl];
#pragma unroll
            for (int j = 0; j < 4; ++j)
                acc[i][j] = __builtin_amdgcn_mfma_f32_16x16x32_bf16(a, bfr[j], acc[i][j], 0, 0, 0);
        }
        __builtin_amdgcn_sched_barrier(0);
        asm volatile("s_waitcnt lgkmcnt(0)" ::: "memory");  // reads in regs
        __builtin_amdgcn_s_barrier();          // WAR: safe to overwrite buf cur
        __builtin_amdgcn_sched_barrier(0);
    }

#pragma unroll
    for (int j = 0; j < 4; ++j) {
        const int oc = oc0 + ow + j * 16 + ln;
        const float s = sc[oc], bb = bi[oc];
#pragma unroll
        for (int i = 0; i < 4; ++i) {
#pragma unroll
            for (int r = 0; r < 4; ++r) {
                const int pos = pos0 + pw + i * 16 + qd * 4 + r;
                float v = s * acc[i][j][r] + bb;
                if constexpr (RELU_OUT) v = fmaxf(v, 0.f);
                if constexpr (RESID) v += u2f(res[(size_t)pos * 256 + oc]);
                if constexpr (NCHW_OUT) {
                    int bb2 = pos / 784, hw = pos - bb2 * 784;
                    ((float*)outp)[((size_t)bb2 * 256 + oc) * 784 + hw] = v;
                } else {
                    ((ushort*)outp)[(size_t)pos * OC + oc] = f2u(v);
                }
            }
        }
    }
}

// ---------------------------------------------------------------------------
// Cascaded group attention: exact round-5 version (176us proven; round-6
// head-top prefetch regressed it to 189us via L2-locality loss — reverted).
// ---------------------------------------------------------------------------
__global__ __launch_bounds__(256, 4) void attn_k(const ushort* __restrict__ X,
                                                 const ushort* __restrict__ qwb,
                                                 const ushort* __restrict__ qbb,
                                                 const ushort* __restrict__ dwvb,
                                                 const ushort* __restrict__ dbbb,
                                                 const float* __restrict__ abx,
                                                 ushort* __restrict__ Y) {
    __shared__ ushort featB[64 * 32];   // feat bf16, pos-major (slot-swizzled)
    __shared__ ushort q2t[64 * 32];     // q after dw5x5 (slot-swizzled)
    __shared__ ushort kt[64 * 32];      // k (slot-swizzled)
    __shared__ ushort vd[32 * 64];      // v, ch-major (swz64)
    __shared__ ushort pt[64 * 64];      // probs, pos-major (swz64)
    __shared__ float  uni[16 * 121];    // q ch-major, 2-wide zero halo (11x11)
    __shared__ ushort dwv[3200];        // all-head dw taps, pre-scaled bf16
    __shared__ ushort qb[512];          // all-head qkv bias bf16
    __shared__ ushort dbl[128];         // all-head dw bias bf16
    __shared__ int    posmap[49];
    __shared__ int    puni[49];

    const int t = threadIdx.x;
    const int w = blockIdx.x;
    const int b = w >> 4, wh = (w >> 2) & 3, ww = w & 3;
    const int wv_ = t >> 6, lane = t & 63;
    const int ln = lane & 15, qd = lane >> 4;
    const int msl = (ln >> 1) & 3;            // slot-XOR for rows ..+ln
    const int fsl = (qd ^ msl) * 8;           // phys frag offset (ushorts)

    if (t < 49) {
        int pi = t / 7, pj = t - pi * 7;
        posmap[t] = b * 784 + (wh * 7 + pi) * 28 + ww * 7 + pj;
        puni[t] = (pi + 2) * 11 + (pj + 2);
    }
    // zero-init (pads never rewritten; swizzles map zero->zero)
    for (int i = t; i < 16 * 121; i += 256) uni[i] = 0.f;
    for (int i = t; i < 64 * 32; i += 256) { q2t[i] = 0; kt[i] = 0; featB[i] = 0; }
    for (int i = t; i < 32 * 64; i += 256) vd[i] = 0;
    for (int i = t; i < 64 * 64; i += 256) pt[i] = 0;
    // stage all-head weights once
    for (int i = t; i < 3200; i += 256) dwv[i] = dwvb[i];
    for (int i = t; i < 512; i += 256) qb[i] = qbb[i];
    if (t < 128) dbl[t] = dbbb[t];
    // feat(head0) = x slice 0 (swizzled store; positions >=49 stay zero)
    for (int i = t; i < 1568; i += 256) {
        int p = i >> 5, c = i & 31;
        int pi = p / 7, pj = p - pi * 7;
        featB[p * 32 + (c & 7) + (((c >> 3) ^ ((p >> 1) & 3)) << 3)] =
            X[(size_t)(b * 784 + (wh * 7 + pi) * 28 + ww * 7 + pj) * 256 + c];
    }
    __syncthreads();

    const int arow = (16 * wv_ + ln) * 32 + fsl;  // swizzled A-frag offset

    for (int head = 0; head < 8; ++head) {
        // ---- qkv: D[o][p] = W'[o][:]·feat[p][:] + b ; wave = o-tile ----
        {
            short8 afr = *(const short8*)&qwb[head * 2048 + (16 * wv_ + ln) * 32 + qd * 8];
            f32x4 acc[4];
#pragma unroll
            for (int j = 0; j < 4; ++j) acc[j] = (f32x4)0.f;
#pragma unroll
            for (int j = 0; j < 4; ++j) {
                short8 bfr = *(const short8*)&featB[(16 * j + ln) * 32 + fsl];
                acc[j] = __builtin_amdgcn_mfma_f32_16x16x32_bf16(afr, bfr, acc[j], 0, 0, 0);
            }
            float qbv[4];
#pragma unroll
            for (int r = 0; r < 4; ++r)
                qbv[r] = u2f(qb[head * 64 + 16 * wv_ + qd * 4 + r]);
#pragma unroll
            for (int j = 0; j < 4; ++j) {
                int p = 16 * j + ln;
                if (p >= 49) continue;
                if (wv_ == 0) {
                    int pu = puni[p];
#pragma unroll
                    for (int r = 0; r < 4; ++r)
                        uni[(qd * 4 + r) * 121 + pu] = acc[j][r] + qbv[r];
                } else if (wv_ == 1) {
                    // logical col qd*4+r -> slot qd>>1, within (qd&1)*4+r
#pragma unroll
                    for (int r = 0; r < 4; ++r)
                        kt[p * 32 + ((qd * 4 + r) & 7) + ((((qd >> 1)) ^ msl) << 3)] =
                            f2u(acc[j][r] + qbv[r]);
                } else {
#pragma unroll
                    for (int r = 0; r < 4; ++r)
                        vd[swz64((wv_ - 2) * 16 + qd * 4 + r, p)] =
                            f2u(acc[j][r] + qbv[r]);
                }
            }
        }
        __syncthreads();   // barrier 1: uni/kt/vd visible to all waves

        // ---- dw5x5 on q: wave computes its own logit rows 16wv_..+15 ----
        {
            const int d = ln;            // fixed per lane -> taps in registers
            float tap[25];
#pragma unroll
            for (int u = 0; u < 25; ++u)
                tap[u] = u2f(dwv[head * 400 + d * 25 + u]);
            float db = u2f(dbl[head * 16 + d]);
#pragma unroll
            for (int k = 0; k < 4; ++k) {
                int p = 16 * wv_ + k * 4 + qd;
                int mq = (2 * k + (qd >> 1)) & 3;   // (p>>1)&3
                if (p < 49) {
                    const float* qp = &uni[d * 121 + (puni[p] - 24)];
                    float a = 0.f;
#pragma unroll
                    for (int u = 0; u < 5; ++u)
#pragma unroll
                        for (int v5 = 0; v5 < 5; ++v5)
                            a += tap[u * 5 + v5] * qp[u * 11 + v5];
                    q2t[p * 32 + (d & 7) + (((d >> 3) ^ mq) << 3)] = f2u(a + db);
                }
            }
        }
        // same-wave q2t write -> read below: DS in-order per wave, no barrier

        // ---- logits + in-register softmax + AV + emit (all per-wave) ----
        {
            short8 afr = *(const short8*)&q2t[arow];
            f32x4 acc[4];
#pragma unroll
            for (int j = 0; j < 4; ++j) acc[j] = (f32x4)0.f;
#pragma unroll
            for (int j = 0; j < 4; ++j) {
                short8 bfr = *(const short8*)&kt[(16 * j + ln) * 32 + fsl];
                acc[j] = __builtin_amdgcn_mfma_f32_16x16x32_bf16(afr, bfr, acc[j], 0, 0, 0);
            }
            const int nbase = 16 * wv_ + qd * 4;
            float lg[4][4];
#pragma unroll
            for (int j = 0; j < 4; ++j) {
                int m = 16 * j + ln;
#pragma unroll
                for (int r = 0; r < 4; ++r) {
                    int n = nbase + r;
                    if (n < 49 && m < 49)
                        lg[j][r] = acc[j][r] * 0.25f + abx[head * 2401 + n * 49 + m];
                    else
                        lg[j][r] = -3e38f;
                }
            }
            float mx[4], sm[4];
#pragma unroll
            for (int r = 0; r < 4; ++r)
                mx[r] = fmaxf(fmaxf(lg[0][r], lg[1][r]), fmaxf(lg[2][r], lg[3][r]));
#pragma unroll
            for (int s = 1; s <= 8; s <<= 1)
#pragma unroll
                for (int r = 0; r < 4; ++r)
                    mx[r] = fmaxf(mx[r], __shfl_xor(mx[r], s, 16));
#pragma unroll
            for (int r = 0; r < 4; ++r) sm[r] = 0.f;
#pragma unroll
            for (int j = 0; j < 4; ++j) {
                int m = 16 * j + ln;
#pragma unroll
                for (int r = 0; r < 4; ++r) {
                    float e = __expf(lg[j][r] - mx[r]);
                    sm[r] += e;
                    int n = nbase + r;
                    if (n < 49 && m < 49) pt[swz64(n, m)] = f2u(e);
                }
            }
#pragma unroll
            for (int s = 1; s <= 8; s <<= 1)
#pragma unroll
                for (int r = 0; r < 4; ++r)
                    sm[r] += __shfl_xor(sm[r], s, 16);
            float inv[4];
#pragma unroll
            for (int r = 0; r < 4; ++r) inv[r] = 1.f / sm[r];

            // AV: D[n][d] = pt[n][:]·vd[d][:]  (swz64 rows share column XOR)
            f32x4 av[2];
            av[0] = (f32x4)0.f; av[1] = (f32x4)0.f;
#pragma unroll
            for (int ks = 0; ks < 2; ++ks) {
                const int cs = (ks * 32 + qd * 8) ^ ((ln & 7) << 3);
                short8 pa = *(const short8*)&pt[(16 * wv_ + ln) * 64 + cs];
#pragma unroll
                for (int dt = 0; dt < 2; ++dt) {
                    short8 vb = *(const short8*)&vd[(16 * dt + ln) * 64 + cs];
                    av[dt] = __builtin_amdgcn_mfma_f32_16x16x32_bf16(pa, vb, av[dt], 0, 0, 0);
                }
            }
            // emit Y slice (ReLU'd for proj) + cascade feat update
#pragma unroll
            for (int r = 0; r < 4; ++r) {
                int n = nbase + r;
                if (n >= 49) continue;
                size_t pbase = (size_t)posmap[n] * 256;
                int mn = (2 * qd + (r >> 1)) & 3;   // (n>>1)&3
#pragma unroll
                for (int dt = 0; dt < 2; ++dt) {
                    int c = 16 * dt + ln;
                    float val = av[dt][r] * inv[r];
                    Y[pbase + head * 32 + c] = f2u(fmaxf(val, 0.f));
                    if (head < 7)
                        featB[n * 32 + (ln & 7) +
                              (((2 * dt + (ln >> 3)) ^ mn) << 3)] =
                            f2u(val + u2f(X[pbase + (head + 1) * 32 + c]));
                }
            }
        }
        __syncthreads();   // barrier 2: featB update visible; buffers reusable
    }
}

// ---------------------------------------------------------------------------
extern "C" void kernel_launch(void* const* d_in, const int* in_sizes, int n_in,
                              void* d_out, int out_size, void* d_ws, size_t ws_size,
                              hipStream_t stream) {
    const float* x       = (const float*)d_in[0];
    const float* dw0_w   = (const float*)d_in[1];
    const float* dw0_s   = (const float*)d_in[2];
    const float* dw0_b   = (const float*)d_in[3];
    const float* ffn0_w1 = (const float*)d_in[4];
    const float* ffn0_s1 = (const float*)d_in[5];
    const float* ffn0_b1 = (const float*)d_in[6];
    const float* ffn0_w2 = (const float*)d_in[7];
    const float* ffn0_s2 = (const float*)d_in[8];
    const float* ffn0_b2 = (const float*)d_in[9];
    const float* qkv_w   = (const float*)d_in[10];
    const float* qkv_s   = (const float*)d_in[11];
    const float* qkv_b   = (const float*)d_in[12];
    const float* dwq_w   = (const float*)d_in[13];
    const float* dwq_s   = (const float*)d_in[14];
    const float* dwq_b   = (const float*)d_in[15];
    const float* attn_b  = (const float*)d_in[16];
    const float* proj_w  = (const float*)d_in[17];
    const float* proj_s  = (const float*)d_in[18];
    const float* proj_b  = (const float*)d_in[19];
    const float* dw1_w   = (const float*)d_in[20];
    const float* dw1_s   = (const float*)d_in[21];
    const float* dw1_b   = (const float*)d_in[22];
    const float* ffn1_w1 = (const float*)d_in[23];
    const float* ffn1_s1 = (const float*)d_in[24];
    const float* ffn1_b1 = (const float*)d_in[25];
    const float* ffn1_w2 = (const float*)d_in[26];
    const float* ffn1_s2 = (const float*)d_in[27];
    const float* ffn1_b2 = (const float*)d_in[28];
    const int*   bidx    = (const int*)d_in[29];

    char* ws = (char*)d_ws;
    const size_t NEL = (size_t)NPOS * 256;
    ushort* wbf = (ushort*)ws;                          // 610048 ushorts
    float*  abx = (float*)(ws + 1220096);               // 76,832 B
    ushort* U0 = (ushort*)(ws + 1220096 + 76832);       // 16B-aligned
    ushort* U1 = U0 + NEL;
    ushort* U2 = U1 + NEL;
    ushort* H  = U2 + NEL;
    const ushort* w1a_b = wbf;
    const ushort* w2a_b = wbf + 131072;
    const ushort* prj_b = wbf + 262144;
    const ushort* w1b_b = wbf + 327680;
    const ushort* w2b_b = wbf + 458752;
    const ushort* qwb   = wbf + 589824;
    const ushort* dwvb  = wbf + 606208;
    const ushort* qbb   = wbf + 609408;
    const ushort* dbbb  = wbf + 609920;

    wcvt_k<<<2383, 256, 0, stream>>>(ffn0_w1, ffn0_w2, proj_w, ffn1_w1, ffn1_w2,
                                     qkv_w, qkv_s, qkv_b, dwq_w, dwq_s, dwq_b, wbf);
    abx_k<<<76, 256, 0, stream>>>(attn_b, bidx, abx);
    tin_k<<<dim3(7, BATCH), 256, 0, stream>>>(x, U0);
    dw3n_k<<<dim3(28, BATCH), 256, 0, stream>>>(U0, dw0_w, dw0_s, dw0_b, U1);
    gemm_k<256, 512, true, false, false>
        <<<dim3(784, 4), 256, 0, stream>>>(U1, w1a_b, ffn0_s1, ffn0_b1, nullptr, H);
    gemm_k<512, 256, false, true, false>
        <<<dim3(784, 2), 256, 0, stream>>>(H, w2a_b, ffn0_s2, ffn0_b2, U1, U2);
    attn_k<<<NWIN, 256, 0, stream>>>(U2, qwb, qbb, dwvb, dbbb, abx, U0);
    gemm_k<256, 256, false, true, false>
        <<<dim3(784, 2), 256, 0, stream>>>(U0, prj_b, proj_s, proj_b, U2, U1);
    dw3n_k<<<dim3(28, BATCH), 256, 0, stream>>>(U1, dw1_w, dw1_s, dw1_b, U2);
    gemm_k<256, 512, true, false, false>
        <<<dim3(784, 4), 256, 0, stream>>>(U2, w1b_b, ffn1_s1, ffn1_b1, nullptr, H);
    gemm_k<512, 256, false, true, true>
        <<<dim3(784, 2), 256, 0, stream>>>(H, w2b_b, ffn1_s2, ffn1_b2, U2, d_out);
}

// Round 10
// 847.079 us; speedup vs baseline: 1.2030x; 1.1403x over previous
//
#include <hip/hip_runtime.h>
#include <hip/hip_bf16.h>

using bf16 = __hip_bfloat16;
using short8 = __attribute__((ext_vector_type(8))) short;
using f32x4  = __attribute__((ext_vector_type(4))) float;

#define BATCH 128
#define CCH   256
#define HWSZ  784
#define NPOS  100352
#define NWIN  2048

__device__ __forceinline__ ushort f2u(float f) {
    bf16 h = __float2bfloat16(f);
    return *reinterpret_cast<ushort*>(&h);
}
__device__ __forceinline__ float u2f(ushort u) {
    bf16 h;
    *reinterpret_cast<ushort*>(&h) = u;
    return __bfloat162float(h);
}
// XOR swizzle for 64-col ushort LDS tiles (128B rows): b128 reads 2-way.
__device__ __forceinline__ int swz64(int row, int col) {
    return row * 64 + (col ^ ((row & 7) << 3));
}
// Async 16B/lane global->LDS (dest = wave-uniform base + lane*16).
__device__ __forceinline__ void gl_lds16(const void* g, void* l) {
    __builtin_amdgcn_global_load_lds(
        (const __attribute__((address_space(1))) void*)g,
        (__attribute__((address_space(3))) void*)l, 16, 0, 0);
}

// ---------------------------------------------------------------------------
// Weight fp32 -> bf16 pre-convert (layout: see offsets in kernel_launch).
// ---------------------------------------------------------------------------
__global__ __launch_bounds__(256) void wcvt_k(const float* __restrict__ w1a,
                                              const float* __restrict__ w2a,
                                              const float* __restrict__ pw,
                                              const float* __restrict__ w1b,
                                              const float* __restrict__ w2b,
                                              const float* __restrict__ qw,
                                              const float* __restrict__ qs,
                                              const float* __restrict__ qbi,
                                              const float* __restrict__ dqw,
                                              const float* __restrict__ dqs,
                                              const float* __restrict__ dqb,
                                              ushort* __restrict__ out) {
    int i = blockIdx.x * 256 + threadIdx.x;
    if (i >= 610048) return;
    float v;
    if (i < 131072)      v = w1a[i];
    else if (i < 262144) v = w2a[i - 131072];
    else if (i < 327680) v = pw[i - 262144];
    else if (i < 458752) v = w1b[i - 327680];
    else if (i < 589824) v = w2b[i - 458752];
    else if (i < 606208) { int j = i - 589824; v = qs[j >> 5] * qw[j]; }
    else if (i < 609408) { int j = i - 606208; v = dqs[j / 25] * dqw[j]; }
    else if (i < 609920) v = qbi[i - 609408];
    else                 v = dqb[i - 609920];
    out[i] = f2u(v);
}

// ---------------------------------------------------------------------------
// Expand attention biases: abx[h][n][m] = ab[h][bidx[n*49+m]]  (8 x 49 x 49)
// ---------------------------------------------------------------------------
__global__ __launch_bounds__(256) void abx_k(const float* __restrict__ ab,
                                             const int* __restrict__ bidx,
                                             float* __restrict__ abx) {
    int i = blockIdx.x * 256 + threadIdx.x;
    if (i >= 8 * 2401) return;
    int h = i / 2401, r = i - h * 2401;
    abx[i] = ab[h * 49 + bidx[r]];
}

// ---------------------------------------------------------------------------
// NCHW fp32 -> NHWC bf16 transpose.
// ---------------------------------------------------------------------------
__global__ __launch_bounds__(256) void tin_k(const float* __restrict__ X,
                                             ushort* __restrict__ O) {
    __shared__ ushort tile[256][113];
    const int pc = blockIdx.x, b = blockIdx.y;
    const int t = threadIdx.x;
    const size_t xbase = (size_t)b * 256 * 784 + pc * 112;
    for (int r = 0; r < 112; ++r) {
        int idx = r * 256 + t;
        int c = idx / 112, p = idx - c * 112;
        tile[c][p] = f2u(X[xbase + (size_t)c * 784 + p]);
    }
    __syncthreads();
    const size_t obase = ((size_t)b * 784 + pc * 112) * 256;
    for (int r = 0; r < 112; ++r) {
        int idx = r * 256 + t;
        int p = idx >> 8, c = idx & 255;
        O[obase + (size_t)p * 256 + c] = tile[c][p];
    }
}

// ---------------------------------------------------------------------------
// Depthwise 3x3 + affine + residual, NHWC bf16 — VECTORIZED (G13).
// Thread = (4-channel group, 1-of-4 w-subset): uint2 8B/lane loads/stores
// (512B/wave-inst, full coalescing) vs the old 2B scalar (128B/wave-inst).
// ---------------------------------------------------------------------------
__global__ __launch_bounds__(256) void dw3n_k(const ushort* __restrict__ X,
                                              const float* __restrict__ Wg,
                                              const float* __restrict__ sc,
                                              const float* __restrict__ bi,
                                              ushort* __restrict__ O) {
    const int h = blockIdx.x, b = blockIdx.y;
    const int t = threadIdx.x;
    const int cg = (t & 63) << 2;       // channel group base (0,4,...,252)
    const int wv = t >> 6;              // wave: handles w = wv, wv+4, ...
    float wt[4][9], s[4], bb[4];
#pragma unroll
    for (int e = 0; e < 4; ++e) {
        int c = cg + e;
#pragma unroll
        for (int k = 0; k < 9; ++k) wt[e][k] = Wg[c * 9 + k];
        s[e] = sc[c]; bb[e] = bi[c];
    }
    const size_t base = (size_t)b * 784 * 256;
    for (int w = wv; w < 28; w += 4) {
        float acc[4] = {0.f, 0.f, 0.f, 0.f};
        float ctr[4] = {0.f, 0.f, 0.f, 0.f};
#pragma unroll
        for (int dh = -1; dh <= 1; ++dh) {
            int hh = h + dh;
            if (hh < 0 || hh >= 28) continue;
#pragma unroll
            for (int dw = -1; dw <= 1; ++dw) {
                int ww = w + dw;
                if (ww < 0 || ww >= 28) continue;
                uint2 xv = *(const uint2*)&X[base + (size_t)(hh * 28 + ww) * 256 + cg];
                ushort xe[4] = {(ushort)(xv.x & 0xffff), (ushort)(xv.x >> 16),
                                (ushort)(xv.y & 0xffff), (ushort)(xv.y >> 16)};
                const int k = (dh + 1) * 3 + (dw + 1);
#pragma unroll
                for (int e = 0; e < 4; ++e) {
                    float x = u2f(xe[e]);
                    if (dh == 0 && dw == 0) ctr[e] = x;
                    acc[e] += wt[e][k] * x;
                }
            }
        }
        uint2 ov;
        ushort o0 = f2u(ctr[0] + s[0] * acc[0] + bb[0]);
        ushort o1 = f2u(ctr[1] + s[1] * acc[1] + bb[1]);
        ushort o2 = f2u(ctr[2] + s[2] * acc[2] + bb[2]);
        ushort o3 = f2u(ctr[3] + s[3] * acc[3] + bb[3]);
        ov.x = (uint)o0 | ((uint)o1 << 16);
        ov.y = (uint)o2 | ((uint)o3 << 16);
        *(uint2*)&O[base + (size_t)(h * 28 + w) * 256 + cg] = ov;
    }
}

// ---------------------------------------------------------------------------
// MFMA GEMM, NHWC. global_load_lds width=16 + counted-vmcnt double buffer
// (neutral vs 2-barrier but not worse; kept) + T1 XCD-aware block swizzle:
// 1-D grid, original order o = x*NY + y (the NY blocks sharing an X panel
// are ADJACENT), chunk swizzle o = (lid&7)*(nwg/8) + lid>>3 (bijective,
// nwg%8==0) -> panel-sharers run back-to-back on the SAME XCD => X panel
// fetched once into that XCD's L2 instead of NY times.
// ---------------------------------------------------------------------------
template <int NY, int IC, int OC, bool RELU_OUT, bool RESID, bool NCHW_OUT>
__global__ __launch_bounds__(256) void gemm_k(const ushort* __restrict__ X,
                                              const ushort* __restrict__ Wb,
                                              const float* __restrict__ sc,
                                              const float* __restrict__ bi,
                                              const ushort* __restrict__ res,
                                              void* __restrict__ outp) {
    __shared__ ushort As[2][128 * 32];
    __shared__ ushort Bs[2][128 * 32];
    const int t = threadIdx.x;
    constexpr int NWG = 784 * NY;
    const int lid = blockIdx.x;
    const int o = (lid & 7) * (NWG >> 3) + (lid >> 3);
    const int pos0 = (o / NY) * 128;
    const int oc0  = (o % NY) * 128;
    const int wave = t >> 6, lane = t & 63;
    const int qd = lane >> 4, ln = lane & 15;
    const int pw = (wave >> 1) * 64, ow = (wave & 1) * 64;
    const int grow = lane >> 2;
    const int gcol = ((lane & 3) ^ ((lane >> 3) & 3)) * 8;
    const int xsl = (qd ^ ((ln >> 1) & 3)) * 8;

    f32x4 acc[4][4];
#pragma unroll
    for (int i = 0; i < 4; ++i)
#pragma unroll
        for (int j = 0; j < 4; ++j) acc[i][j] = (f32x4)0.f;

    constexpr int NT = IC / 32;
    // prologue: stage tile 0 into buf 0 (4 DMA/wave)
#pragma unroll
    for (int r = 0; r < 2; ++r) {
        const int rowbase = wave * 16 + r * 64;
        gl_lds16(&X[(size_t)(pos0 + rowbase + grow) * IC + gcol], &As[0][rowbase * 32]);
        gl_lds16(&Wb[(size_t)(oc0 + rowbase + grow) * IC + gcol], &Bs[0][rowbase * 32]);
    }

    for (int kt = 0; kt < NT; ++kt) {
        const int cur = kt & 1;
        if (kt + 1 < NT) {
            const int k0 = (kt + 1) * 32;
#pragma unroll
            for (int r = 0; r < 2; ++r) {
                const int rowbase = wave * 16 + r * 64;
                gl_lds16(&X[(size_t)(pos0 + rowbase + grow) * IC + k0 + gcol],
                         &As[cur ^ 1][rowbase * 32]);
                gl_lds16(&Wb[(size_t)(oc0 + rowbase + grow) * IC + k0 + gcol],
                         &Bs[cur ^ 1][rowbase * 32]);
            }
            asm volatile("s_waitcnt vmcnt(4)" ::: "memory");  // tile kt landed
        } else {
            asm volatile("s_waitcnt vmcnt(0)" ::: "memory");  // last tile
        }
        __builtin_amdgcn_sched_barrier(0);
        __builtin_amdgcn_s_barrier();          // all waves' tile-kt DMA landed
        __builtin_amdgcn_sched_barrier(0);

        short8 bfr[4];
#pragma unroll
        for (int j = 0; j < 4; ++j)
            bfr[j] = *(const short8*)&Bs[cur][(ow + j * 16 + ln) * 32 + xsl];
#pragma unroll
        for (int i = 0; i < 4; ++i) {
            short8 a = *(const short8*)&As[cur][(pw + i * 16 + ln) * 32 + xsl];
#pragma unroll
            for (int j = 0; j < 4; ++j)
                acc[i][j] = __builtin_amdgcn_mfma_f32_16x16x32_bf16(a, bfr[j], acc[i][j], 0, 0, 0);
        }
        __builtin_amdgcn_sched_barrier(0);
        asm volatile("s_waitcnt lgkmcnt(0)" ::: "memory");  // reads in regs
        __builtin_amdgcn_s_barrier();          // WAR: safe to overwrite buf cur
        __builtin_amdgcn_sched_barrier(0);
    }

#pragma unroll
    for (int j = 0; j < 4; ++j) {
        const int oc = oc0 + ow + j * 16 + ln;
        const float s = sc[oc], bb = bi[oc];
#pragma unroll
        for (int i = 0; i < 4; ++i) {
#pragma unroll
            for (int r = 0; r < 4; ++r) {
                const int pos = pos0 + pw + i * 16 + qd * 4 + r;
                float v = s * acc[i][j][r] + bb;
                if constexpr (RELU_OUT) v = fmaxf(v, 0.f);
                if constexpr (RESID) v += u2f(res[(size_t)pos * 256 + oc]);
                if constexpr (NCHW_OUT) {
                    int bb2 = pos / 784, hw = pos - bb2 * 784;
                    ((float*)outp)[((size_t)bb2 * 256 + oc) * 784 + hw] = v;
                } else {
                    ((ushort*)outp)[(size_t)pos * OC + oc] = f2u(v);
                }
            }
        }
    }
}

// ---------------------------------------------------------------------------
// Cascaded group attention: exact round-5/8 version (175us proven).
// ---------------------------------------------------------------------------
__global__ __launch_bounds__(256, 4) void attn_k(const ushort* __restrict__ X,
                                                 const ushort* __restrict__ qwb,
                                                 const ushort* __restrict__ qbb,
                                                 const ushort* __restrict__ dwvb,
                                                 const ushort* __restrict__ dbbb,
                                                 const float* __restrict__ abx,
                                                 ushort* __restrict__ Y) {
    __shared__ ushort featB[64 * 32];   // feat bf16, pos-major (slot-swizzled)
    __shared__ ushort q2t[64 * 32];     // q after dw5x5 (slot-swizzled)
    __shared__ ushort kt[64 * 32];      // k (slot-swizzled)
    __shared__ ushort vd[32 * 64];      // v, ch-major (swz64)
    __shared__ ushort pt[64 * 64];      // probs, pos-major (swz64)
    __shared__ float  uni[16 * 121];    // q ch-major, 2-wide zero halo (11x11)
    __shared__ ushort dwv[3200];        // all-head dw taps, pre-scaled bf16
    __shared__ ushort qb[512];          // all-head qkv bias bf16
    __shared__ ushort dbl[128];         // all-head dw bias bf16
    __shared__ int    posmap[49];
    __shared__ int    puni[49];

    const int t = threadIdx.x;
    const int w = blockIdx.x;
    const int b = w >> 4, wh = (w >> 2) & 3, ww = w & 3;
    const int wv_ = t >> 6, lane = t & 63;
    const int ln = lane & 15, qd = lane >> 4;
    const int msl = (ln >> 1) & 3;            // slot-XOR for rows ..+ln
    const int fsl = (qd ^ msl) * 8;           // phys frag offset (ushorts)

    if (t < 49) {
        int pi = t / 7, pj = t - pi * 7;
        posmap[t] = b * 784 + (wh * 7 + pi) * 28 + ww * 7 + pj;
        puni[t] = (pi + 2) * 11 + (pj + 2);
    }
    // zero-init (pads never rewritten; swizzles map zero->zero)
    for (int i = t; i < 16 * 121; i += 256) uni[i] = 0.f;
    for (int i = t; i < 64 * 32; i += 256) { q2t[i] = 0; kt[i] = 0; featB[i] = 0; }
    for (int i = t; i < 32 * 64; i += 256) vd[i] = 0;
    for (int i = t; i < 64 * 64; i += 256) pt[i] = 0;
    // stage all-head weights once
    for (int i = t; i < 3200; i += 256) dwv[i] = dwvb[i];
    for (int i = t; i < 512; i += 256) qb[i] = qbb[i];
    if (t < 128) dbl[t] = dbbb[t];
    // feat(head0) = x slice 0 (swizzled store; positions >=49 stay zero)
    for (int i = t; i < 1568; i += 256) {
        int p = i >> 5, c = i & 31;
        int pi = p / 7, pj = p - pi * 7;
        featB[p * 32 + (c & 7) + (((c >> 3) ^ ((p >> 1) & 3)) << 3)] =
            X[(size_t)(b * 784 + (wh * 7 + pi) * 28 + ww * 7 + pj) * 256 + c];
    }
    __syncthreads();

    const int arow = (16 * wv_ + ln) * 32 + fsl;  // swizzled A-frag offset

    for (int head = 0; head < 8; ++head) {
        // ---- qkv: D[o][p] = W'[o][:]·feat[p][:] + b ; wave = o-tile ----
        {
            short8 afr = *(const short8*)&qwb[head * 2048 + (16 * wv_ + ln) * 32 + qd * 8];
            f32x4 acc[4];
#pragma unroll
            for (int j = 0; j < 4; ++j) acc[j] = (f32x4)0.f;
#pragma unroll
            for (int j = 0; j < 4; ++j) {
                short8 bfr = *(const short8*)&featB[(16 * j + ln) * 32 + fsl];
                acc[j] = __builtin_amdgcn_mfma_f32_16x16x32_bf16(afr, bfr, acc[j], 0, 0, 0);
            }
            float qbv[4];
#pragma unroll
            for (int r = 0; r < 4; ++r)
                qbv[r] = u2f(qb[head * 64 + 16 * wv_ + qd * 4 + r]);
#pragma unroll
            for (int j = 0; j < 4; ++j) {
                int p = 16 * j + ln;
                if (p >= 49) continue;
                if (wv_ == 0) {
                    int pu = puni[p];
#pragma unroll
                    for (int r = 0; r < 4; ++r)
                        uni[(qd * 4 + r) * 121 + pu] = acc[j][r] + qbv[r];
                } else if (wv_ == 1) {
                    // logical col qd*4+r -> slot qd>>1, within (qd&1)*4+r
#pragma unroll
                    for (int r = 0; r < 4; ++r)
                        kt[p * 32 + ((qd * 4 + r) & 7) + ((((qd >> 1)) ^ msl) << 3)] =
                            f2u(acc[j][r] + qbv[r]);
                } else {
#pragma unroll
                    for (int r = 0; r < 4; ++r)
                        vd[swz64((wv_ - 2) * 16 + qd * 4 + r, p)] =
                            f2u(acc[j][r] + qbv[r]);
                }
            }
        }
        __syncthreads();   // barrier 1: uni/kt/vd visible to all waves

        // ---- dw5x5 on q: wave computes its own logit rows 16wv_..+15 ----
        {
            const int d = ln;            // fixed per lane -> taps in registers
            float tap[25];
#pragma unroll
            for (int u = 0; u < 25; ++u)
                tap[u] = u2f(dwv[head * 400 + d * 25 + u]);
            float db = u2f(dbl[head * 16 + d]);
#pragma unroll
            for (int k = 0; k < 4; ++k) {
                int p = 16 * wv_ + k * 4 + qd;
                int mq = (2 * k + (qd >> 1)) & 3;   // (p>>1)&3
                if (p < 49) {
                    const float* qp = &uni[d * 121 + (puni[p] - 24)];
                    float a = 0.f;
#pragma unroll
                    for (int u = 0; u < 5; ++u)
#pragma unroll
                        for (int v5 = 0; v5 < 5; ++v5)
                            a += tap[u * 5 + v5] * qp[u * 11 + v5];
                    q2t[p * 32 + (d & 7) + (((d >> 3) ^ mq) << 3)] = f2u(a + db);
                }
            }
        }
        // same-wave q2t write -> read below: DS in-order per wave, no barrier

        // ---- logits + in-register softmax + AV + emit (all per-wave) ----
        {
            short8 afr = *(const short8*)&q2t[arow];
            f32x4 acc[4];
#pragma unroll
            for (int j = 0; j < 4; ++j) acc[j] = (f32x4)0.f;
#pragma unroll
            for (int j = 0; j < 4; ++j) {
                short8 bfr = *(const short8*)&kt[(16 * j + ln) * 32 + fsl];
                acc[j] = __builtin_amdgcn_mfma_f32_16x16x32_bf16(afr, bfr, acc[j], 0, 0, 0);
            }
            const int nbase = 16 * wv_ + qd * 4;
            float lg[4][4];
#pragma unroll
            for (int j = 0; j < 4; ++j) {
                int m = 16 * j + ln;
#pragma unroll
                for (int r = 0; r < 4; ++r) {
                    int n = nbase + r;
                    if (n < 49 && m < 49)
                        lg[j][r] = acc[j][r] * 0.25f + abx[head * 2401 + n * 49 + m];
                    else
                        lg[j][r] = -3e38f;
                }
            }
            float mx[4], sm[4];
#pragma unroll
            for (int r = 0; r < 4; ++r)
                mx[r] = fmaxf(fmaxf(lg[0][r], lg[1][r]), fmaxf(lg[2][r], lg[3][r]));
#pragma unroll
            for (int s = 1; s <= 8; s <<= 1)
#pragma unroll
                for (int r = 0; r < 4; ++r)
                    mx[r] = fmaxf(mx[r], __shfl_xor(mx[r], s, 16));
#pragma unroll
            for (int r = 0; r < 4; ++r) sm[r] = 0.f;
#pragma unroll
            for (int j = 0; j < 4; ++j) {
                int m = 16 * j + ln;
#pragma unroll
                for (int r = 0; r < 4; ++r) {
                    float e = __expf(lg[j][r] - mx[r]);
                    sm[r] += e;
                    int n = nbase + r;
                    if (n < 49 && m < 49) pt[swz64(n, m)] = f2u(e);
                }
            }
#pragma unroll
            for (int s = 1; s <= 8; s <<= 1)
#pragma unroll
                for (int r = 0; r < 4; ++r)
                    sm[r] += __shfl_xor(sm[r], s, 16);
            float inv[4];
#pragma unroll
            for (int r = 0; r < 4; ++r) inv[r] = 1.f / sm[r];

            // AV: D[n][d] = pt[n][:]·vd[d][:]  (swz64 rows share column XOR)
            f32x4 av[2];
            av[0] = (f32x4)0.f; av[1] = (f32x4)0.f;
#pragma unroll
            for (int ks = 0; ks < 2; ++ks) {
                const int cs = (ks * 32 + qd * 8) ^ ((ln & 7) << 3);
                short8 pa = *(const short8*)&pt[(16 * wv_ + ln) * 64 + cs];
#pragma unroll
                for (int dt = 0; dt < 2; ++dt) {
                    short8 vb = *(const short8*)&vd[(16 * dt + ln) * 64 + cs];
                    av[dt] = __builtin_amdgcn_mfma_f32_16x16x32_bf16(pa, vb, av[dt], 0, 0, 0);
                }
            }
            // emit Y slice (ReLU'd for proj) + cascade feat update
#pragma unroll
            for (int r = 0; r < 4; ++r) {
                int n = nbase + r;
                if (n >= 49) continue;
                size_t pbase = (size_t)posmap[n] * 256;
                int mn = (2 * qd + (r >> 1)) & 3;   // (n>>1)&3
#pragma unroll
                for (int dt = 0; dt < 2; ++dt) {
                    int c = 16 * dt + ln;
                    float val = av[dt][r] * inv[r];
                    Y[pbase + head * 32 + c] = f2u(fmaxf(val, 0.f));
                    if (head < 7)
                        featB[n * 32 + (ln & 7) +
                              (((2 * dt + (ln >> 3)) ^ mn) << 3)] =
                            f2u(val + u2f(X[pbase + (head + 1) * 32 + c]));
                }
            }
        }
        __syncthreads();   // barrier 2: featB update visible; buffers reusable
    }
}

// ---------------------------------------------------------------------------
extern "C" void kernel_launch(void* const* d_in, const int* in_sizes, int n_in,
                              void* d_out, int out_size, void* d_ws, size_t ws_size,
                              hipStream_t stream) {
    const float* x       = (const float*)d_in[0];
    const float* dw0_w   = (const float*)d_in[1];
    const float* dw0_s   = (const float*)d_in[2];
    const float* dw0_b   = (const float*)d_in[3];
    const float* ffn0_w1 = (const float*)d_in[4];
    const float* ffn0_s1 = (const float*)d_in[5];
    const float* ffn0_b1 = (const float*)d_in[6];
    const float* ffn0_w2 = (const float*)d_in[7];
    const float* ffn0_s2 = (const float*)d_in[8];
    const float* ffn0_b2 = (const float*)d_in[9];
    const float* qkv_w   = (const float*)d_in[10];
    const float* qkv_s   = (const float*)d_in[11];
    const float* qkv_b   = (const float*)d_in[12];
    const float* dwq_w   = (const float*)d_in[13];
    const float* dwq_s   = (const float*)d_in[14];
    const float* dwq_b   = (const float*)d_in[15];
    const float* attn_b  = (const float*)d_in[16];
    const float* proj_w  = (const float*)d_in[17];
    const float* proj_s  = (const float*)d_in[18];
    const float* proj_b  = (const float*)d_in[19];
    const float* dw1_w   = (const float*)d_in[20];
    const float* dw1_s   = (const float*)d_in[21];
    const float* dw1_b   = (const float*)d_in[22];
    const float* ffn1_w1 = (const float*)d_in[23];
    const float* ffn1_s1 = (const float*)d_in[24];
    const float* ffn1_b1 = (const float*)d_in[25];
    const float* ffn1_w2 = (const float*)d_in[26];
    const float* ffn1_s2 = (const float*)d_in[27];
    const float* ffn1_b2 = (const float*)d_in[28];
    const int*   bidx    = (const int*)d_in[29];

    char* ws = (char*)d_ws;
    const size_t NEL = (size_t)NPOS * 256;
    ushort* wbf = (ushort*)ws;                          // 610048 ushorts
    float*  abx = (float*)(ws + 1220096);               // 76,832 B
    ushort* U0 = (ushort*)(ws + 1220096 + 76832);       // 16B-aligned
    ushort* U1 = U0 + NEL;
    ushort* U2 = U1 + NEL;
    ushort* H  = U2 + NEL;
    const ushort* w1a_b = wbf;
    const ushort* w2a_b = wbf + 131072;
    const ushort* prj_b = wbf + 262144;
    const ushort* w1b_b = wbf + 327680;
    const ushort* w2b_b = wbf + 458752;
    const ushort* qwb   = wbf + 589824;
    const ushort* dwvb  = wbf + 606208;
    const ushort* qbb   = wbf + 609408;
    const ushort* dbbb  = wbf + 609920;

    wcvt_k<<<2383, 256, 0, stream>>>(ffn0_w1, ffn0_w2, proj_w, ffn1_w1, ffn1_w2,
                                     qkv_w, qkv_s, qkv_b, dwq_w, dwq_s, dwq_b, wbf);
    abx_k<<<76, 256, 0, stream>>>(attn_b, bidx, abx);
    tin_k<<<dim3(7, BATCH), 256, 0, stream>>>(x, U0);
    dw3n_k<<<dim3(28, BATCH), 256, 0, stream>>>(U0, dw0_w, dw0_s, dw0_b, U1);
    gemm_k<4, 256, 512, true, false, false>
        <<<3136, 256, 0, stream>>>(U1, w1a_b, ffn0_s1, ffn0_b1, nullptr, H);
    gemm_k<2, 512, 256, false, true, false>
        <<<1568, 256, 0, stream>>>(H, w2a_b, ffn0_s2, ffn0_b2, U1, U2);
    attn_k<<<NWIN, 256, 0, stream>>>(U2, qwb, qbb, dwvb, dbbb, abx, U0);
    gemm_k<2, 256, 256, false, true, false>
        <<<1568, 256, 0, stream>>>(U0, prj_b, proj_s, proj_b, U2, U1);
    dw3n_k<<<dim3(28, BATCH), 256, 0, stream>>>(U1, dw1_w, dw1_s, dw1_b, U2);
    gemm_k<4, 256, 512, true, false, false>
        <<<3136, 256, 0, stream>>>(U2, w1b_b, ffn1_s1, ffn1_b1, nullptr, H);
    gemm_k<2, 512, 256, false, true, true>
        <<<1568, 256, 0, stream>>>(H, w2b_b, ffn1_s2, ffn1_b2, U2, d_out);
}